// Round 6
// baseline (520.029 us; speedup 1.0000x reference)
//
#include <hip/hip_runtime.h>
#include <stdint.h>

// MLA bf16-MFMA pipeline R6. B=2, N=2048, D=1024, L=512, H=16, Dh=64.
// Flash rewritten: S^T = K*Q^T (swapped MFMA operands) makes softmax
// within-lane (2 shuffles instead of 32), P-writes b64-vectorized, and K/V
// fragments load direct global->VGPR (no LDS staging, ZERO barriers in the
// K-loop). LDS = P roundtrip only (9 KB). GEMM pipeline unchanged from R5.

typedef __attribute__((ext_vector_type(8))) __bf16 bf16x8;
typedef __attribute__((ext_vector_type(4))) float f32x4;

__device__ inline unsigned short f2bfu(float f) {
    __bf16 b = (__bf16)f;
    return __builtin_bit_cast(unsigned short, b);
}

__device__ inline float exp2_fast(float f) {
    return __builtin_amdgcn_exp2f(f);   // raw v_exp_f32
}

__device__ inline void load_lds16(const void* g, void* l) {
    __builtin_amdgcn_global_load_lds(
        (const __attribute__((address_space(1))) uint32_t*)g,
        (__attribute__((address_space(3))) uint32_t*)l, 16, 0, 0);
}

__device__ inline f32x4 mfma_bf16(bf16x8 a, bf16x8 b, f32x4 c) {
    return __builtin_amdgcn_mfma_f32_16x16x32_bf16(a, b, c, 0, 0, 0);
}

// ---------------- prep kernels ----------------

__global__ __launch_bounds__(256) void cvt_x_kernel(
    const float* __restrict__ src, unsigned short* __restrict__ dst)
{
    int i = (blockIdx.x * 256 + threadIdx.x) * 4;
    float4 v = *(const float4*)&src[i];
    ushort4 o;
    o.x = f2bfu(v.x); o.y = f2bfu(v.y); o.z = f2bfu(v.z); o.w = f2bfu(v.w);
    *(ushort4*)&dst[i] = o;
}

// z-batched: src f32 [R][C] -> dst bf16 [C][R] * scale. grid (C/64, R/64, nz)
__global__ __launch_bounds__(256) void transpose_w2_kernel(
    const float* __restrict__ s0, const float* __restrict__ s1,
    unsigned short* __restrict__ d0, unsigned short* __restrict__ d1,
    int R, int C, float sc0, float sc1)
{
    const float* src = blockIdx.z ? s1 : s0;
    unsigned short* dst = blockIdx.z ? d1 : d0;
    float sc = blockIdx.z ? sc1 : sc0;
    __shared__ float tile[64][65];
    int c0 = blockIdx.x * 64, r0 = blockIdx.y * 64;
    int t = threadIdx.x;
    int col = t & 63, rr = t >> 6;
#pragma unroll
    for (int i = 0; i < 16; ++i)
        tile[rr + i * 4][col] = src[(size_t)(r0 + rr + i * 4) * C + c0 + col];
    __syncthreads();
#pragma unroll
    for (int i = 0; i < 16; ++i) {
        int r2 = rr + i * 4;
        dst[(size_t)(c0 + r2) * R + r0 + col] = f2bfu(tile[col][r2] * sc);
    }
}

// v[b][n][h*64+d] (ld ldv) bf16 -> vt[(b*16+h)*64+d][n]. grid (2048/64, 32)
__global__ __launch_bounds__(256) void transpose_v_kernel(
    const unsigned short* __restrict__ v, int ldv, unsigned short* __restrict__ vt)
{
    __shared__ unsigned short tile[64][65];
    int n0 = blockIdx.x * 64, bh = blockIdx.y;
    int b = bh >> 4, h = bh & 15;
    int t = threadIdx.x;
    int r = t >> 3, c = t & 7;
#pragma unroll
    for (int p = 0; p < 2; ++p) {
        int row = r + p * 32;
        const unsigned short* src = v + (size_t)(b * 2048 + n0 + row) * ldv + h * 64 + c * 8;
        ushort4 a = *(const ushort4*)src;
        ushort4 b4 = *(const ushort4*)(src + 4);
        tile[row][c * 8 + 0] = a.x;  tile[row][c * 8 + 1] = a.y;
        tile[row][c * 8 + 2] = a.z;  tile[row][c * 8 + 3] = a.w;
        tile[row][c * 8 + 4] = b4.x; tile[row][c * 8 + 5] = b4.y;
        tile[row][c * 8 + 6] = b4.z; tile[row][c * 8 + 7] = b4.w;
    }
    __syncthreads();
#pragma unroll
    for (int p = 0; p < 2; ++p) {
        int d = r + p * 32;
        ushort4 o0, o1;
        o0.x = tile[c * 8 + 0][d]; o0.y = tile[c * 8 + 1][d];
        o0.z = tile[c * 8 + 2][d]; o0.w = tile[c * 8 + 3][d];
        o1.x = tile[c * 8 + 4][d]; o1.y = tile[c * 8 + 5][d];
        o1.z = tile[c * 8 + 6][d]; o1.w = tile[c * 8 + 7][d];
        unsigned short* dp = vt + (size_t)(bh * 64 + d) * 2048 + n0 + c * 8;
        *(ushort4*)dp = o0;
        *(ushort4*)(dp + 4) = o1;
    }
}

// ---------------- bf16 MFMA GEMM (m97 structure, z-batched) ----------------
// C[M][N] = A[M][K] @ Bt[N][K]^T (+bias)(relu). 128x128 tile, BK=32.
// grid (N/128, M/128, nz), block 256.
__global__ __launch_bounds__(256) void gemm_bf16_kernel(
    const unsigned short* __restrict__ A0, const unsigned short* __restrict__ A1,
    const unsigned short* __restrict__ B0, const unsigned short* __restrict__ B1,
    void* __restrict__ C0, void* __restrict__ C1,
    int lda, int ldb, int ldc, int K,
    const float* __restrict__ bias, int relu, int out_f32)
{
    const unsigned short* A = blockIdx.z ? A1 : A0;
    const unsigned short* Bt = blockIdx.z ? B1 : B0;
    void* C = blockIdx.z ? C1 : C0;

    __shared__ unsigned short Als[128 * 32];
    __shared__ unsigned short Bls[128 * 32];
    int t = threadIdx.x;
    int lane = t & 63, w = t >> 6;
    int n0 = blockIdx.x * 128, m0 = blockIdx.y * 128;
    int wm = (w & 1) * 64, wn = (w >> 1) * 64;
    int lrow = lane & 15, quad = lane >> 4;

    f32x4 acc[4][4];
    f32x4 z = {0.f, 0.f, 0.f, 0.f};
#pragma unroll
    for (int i = 0; i < 4; ++i)
#pragma unroll
        for (int j = 0; j < 4; ++j) acc[i][j] = z;

    int c0 = t, c1 = t + 256;
    const unsigned short* ag0 = A + (size_t)(m0 + (c0 >> 2)) * lda + (c0 & 3) * 8;
    const unsigned short* ag1 = A + (size_t)(m0 + (c1 >> 2)) * lda + (c1 & 3) * 8;
    const unsigned short* bg0 = Bt + (size_t)(n0 + (c0 >> 2)) * ldb + (c0 & 3) * 8;
    const unsigned short* bg1 = Bt + (size_t)(n0 + (c1 >> 2)) * ldb + (c1 & 3) * 8;

    for (int k0 = 0; k0 < K; k0 += 32) {
        __syncthreads();
        load_lds16(ag0 + k0, &Als[c0 * 8]);
        load_lds16(ag1 + k0, &Als[c1 * 8]);
        load_lds16(bg0 + k0, &Bls[c0 * 8]);
        load_lds16(bg1 + k0, &Bls[c1 * 8]);
        __syncthreads();

        bf16x8 af[4], bfr[4];
#pragma unroll
        for (int mi = 0; mi < 4; ++mi)
            af[mi] = *(const bf16x8*)&Als[(wm + mi * 16 + lrow) * 32 + quad * 8];
#pragma unroll
        for (int ni = 0; ni < 4; ++ni)
            bfr[ni] = *(const bf16x8*)&Bls[(wn + ni * 16 + lrow) * 32 + quad * 8];
#pragma unroll
        for (int mi = 0; mi < 4; ++mi)
#pragma unroll
            for (int ni = 0; ni < 4; ++ni)
                acc[mi][ni] = mfma_bf16(af[mi], bfr[ni], acc[mi][ni]);
    }

#pragma unroll
    for (int mi = 0; mi < 4; ++mi)
#pragma unroll
        for (int ni = 0; ni < 4; ++ni)
#pragma unroll
            for (int r = 0; r < 4; ++r) {
                int row = m0 + wm + mi * 16 + quad * 4 + r;
                int col = n0 + wn + ni * 16 + lrow;
                float v = acc[mi][ni][r];
                if (bias) v += bias[col];
                if (relu) v = fmaxf(v, 0.0f);
                if (out_f32) ((float*)C)[(size_t)row * ldc + col] = v;
                else ((unsigned short*)C)[(size_t)row * ldc + col] = f2bfu(v);
            }
}

// ---------------- MFMA flash attention, barrier-free ----------------
// Q (ldq, scaled by 0.125*log2e) / K (ldk): head-interleaved [4096][ld];
// Vt: [32*64][2048]. grid (2048/64, 32), block 256 (4 waves), wave w owns
// q-rows w*16..+15. S^T = K*Q^T so softmax is within-lane; K/V frags are
// direct global->VGPR dwordx4 loads (wave-coalesced to 64B/row); LDS only
// for the P C-layout -> A-layout roundtrip (wave-local, no __syncthreads).
__global__ __launch_bounds__(256) void flash_mfma_kernel(
    const unsigned short* __restrict__ Q, int ldq,
    const unsigned short* __restrict__ K, int ldk,
    const unsigned short* __restrict__ Vt, unsigned short* __restrict__ O)
{
    __shared__ unsigned short Pls[4][16 * 72];   // per-wave P, stride 72 (2-way banks = free)

    int q0 = blockIdx.x * 64, bh = blockIdx.y;
    int b = bh >> 4, h = bh & 15;
    int t = threadIdx.x;
    int lane = t & 63, w = t >> 6;
    int lrow = lane & 15, quad = lane >> 4;

    // Q fragment: lane holds Q[qrow=lrow][d=quad*8+j] — serves as B-operand
    const unsigned short* qrow = Q + (size_t)(b * 2048 + q0 + w * 16 + lrow) * ldq + h * 64;
    bf16x8 qf0 = *(const bf16x8*)&qrow[quad * 8];
    bf16x8 qf1 = *(const bf16x8*)&qrow[32 + quad * 8];

    f32x4 z = {0.f, 0.f, 0.f, 0.f};
    f32x4 acco[4];   // O[qrow=quad*4+r][d=nt*16+lrow]
#pragma unroll
    for (int i = 0; i < 4; ++i) acco[i] = z;
    float m_run = -1e30f, l_run = 0.f;   // per-lane: q-row = lrow (replicated x4 quads)

    // K frag base: row (kt + nt*16 + lrow), 16B at d-offset quad*8
    const unsigned short* kbase = K + (size_t)(b * 2048 + lrow) * ldk + h * 64 + quad * 8;
    // V frag base: Vt row (bh*64 + nt*16 + lrow), 16B at kv-offset kt + ks*32 + quad*8
    const unsigned short* vbase = Vt + (size_t)(bh * 64 + lrow) * 2048 + quad * 8;

    for (int kt = 0; kt < 2048; kt += 64) {
        // K fragments (A-operand): direct global->VGPR
        bf16x8 kf0[4], kf1[4];
#pragma unroll
        for (int nt = 0; nt < 4; ++nt) {
            const unsigned short* kr = kbase + (size_t)(kt + nt * 16) * ldk;
            kf0[nt] = *(const bf16x8*)kr;
            kf1[nt] = *(const bf16x8*)(kr + 32);
        }

        // S^T = K * Q^T : lane -> S^T[kv=nt*16+quad*4+r][qrow=lrow]
        f32x4 s[4];
#pragma unroll
        for (int nt = 0; nt < 4; ++nt) {
            s[nt] = mfma_bf16(kf0[nt], qf0, z);
            s[nt] = mfma_bf16(kf1[nt], qf1, s[nt]);
        }

        // V fragments (B-operand) issued now, consumed after softmax
        bf16x8 vf[4][2];
#pragma unroll
        for (int nt = 0; nt < 4; ++nt) {
            const unsigned short* vr = vbase + (size_t)(nt * 16) * 2048 + kt;
            vf[nt][0] = *(const bf16x8*)vr;
            vf[nt][1] = *(const bf16x8*)(vr + 32);
        }

        // online softmax (log2 domain), within-lane over 16 kv values
        float mx01 = fmaxf(fmaxf(s[0][0], s[0][1]), fmaxf(s[0][2], s[0][3]));
        float mx23 = fmaxf(fmaxf(s[1][0], s[1][1]), fmaxf(s[1][2], s[1][3]));
        float mx45 = fmaxf(fmaxf(s[2][0], s[2][1]), fmaxf(s[2][2], s[2][3]));
        float mx67 = fmaxf(fmaxf(s[3][0], s[3][1]), fmaxf(s[3][2], s[3][3]));
        float mx = fmaxf(fmaxf(mx01, mx23), fmaxf(mx45, mx67));
        mx = fmaxf(mx, __shfl_xor(mx, 16, 64));
        mx = fmaxf(mx, __shfl_xor(mx, 32, 64));
        float mnew = fmaxf(m_run, mx);
        float al = exp2_fast(m_run - mnew);
        m_run = mnew;

        float rs = 0.f;
#pragma unroll
        for (int nt = 0; nt < 4; ++nt)
#pragma unroll
            for (int r = 0; r < 4; ++r) {
                float pv = exp2_fast(s[nt][r] - mnew);
                s[nt][r] = pv;
                rs += pv;
            }
        rs += __shfl_xor(rs, 16, 64);
        rs += __shfl_xor(rs, 32, 64);
        l_run = l_run * al + rs;

        // rescale acco: alpha of q-row quad*4+r lives at lane (quad*4+r)
        float alr[4];
#pragma unroll
        for (int r = 0; r < 4; ++r) alr[r] = __shfl(al, quad * 4 + r, 64);
#pragma unroll
        for (int nt = 0; nt < 4; ++nt)
#pragma unroll
            for (int r = 0; r < 4; ++r) acco[nt][r] *= alr[r];

        // P: pack 4 kv-consecutive bf16 per tile -> b64 write (wave-local)
#pragma unroll
        for (int nt = 0; nt < 4; ++nt) {
            ushort4 pk;
            pk.x = f2bfu(s[nt][0]); pk.y = f2bfu(s[nt][1]);
            pk.z = f2bfu(s[nt][2]); pk.w = f2bfu(s[nt][3]);
            *(ushort4*)&Pls[w][lrow * 72 + nt * 16 + quad * 4] = pk;
        }
        bf16x8 pf0 = *(const bf16x8*)&Pls[w][lrow * 72 + quad * 8];
        bf16x8 pf1 = *(const bf16x8*)&Pls[w][lrow * 72 + 32 + quad * 8];

        // O += P @ V
#pragma unroll
        for (int nt = 0; nt < 4; ++nt) {
            acco[nt] = mfma_bf16(pf0, vf[nt][0], acco[nt]);
            acco[nt] = mfma_bf16(pf1, vf[nt][1], acco[nt]);
        }
    }

    // epilogue: l for q-row quad*4+r via shuffle
#pragma unroll
    for (int r = 0; r < 4; ++r) {
        float lr = __shfl(l_run, quad * 4 + r, 64);
        float rl = 1.0f / lr;
        int row = b * 2048 + q0 + w * 16 + quad * 4 + r;
#pragma unroll
        for (int nt = 0; nt < 4; ++nt)
            O[(size_t)row * 1024 + h * 64 + nt * 16 + lrow] = f2bfu(acco[nt][r] * rl);
    }
}

// ---------------- launch ----------------

extern "C" void kernel_launch(void* const* d_in, const int* in_sizes, int n_in,
                              void* d_out, int out_size, void* d_ws, size_t ws_size,
                              hipStream_t stream) {
    const float* x   = (const float*)d_in[0];
    const float* Wq  = (const float*)d_in[1];
    const float* Wkv = (const float*)d_in[2];
    const float* Wk1 = (const float*)d_in[3];
    const float* Wk2 = (const float*)d_in[4];
    const float* Wv1 = (const float*)d_in[5];
    const float* Wv2 = (const float*)d_in[6];
    const float* Wo  = (const float*)d_in[7];
    const float* bo  = (const float*)d_in[8];
    float* out = (float*)d_out;

    unsigned short* p = (unsigned short*)d_ws;
    unsigned short* xb    = p; p += 4194304;   // [4096][1024]
    unsigned short* WqkvT = p; p += 3145728;   // [3072][1024]  (Wq^T scaled | Wkv^T)
    unsigned short* WoT   = p; p += 1048576;   // [1024][1024]
    unsigned short* Wk1T  = p; p += 524288;    // [512][1024]
    unsigned short* Wv1T  = p; p += 524288;    // [512][1024]
    unsigned short* Wk2T  = p; p += 524288;    // [1024][512]
    unsigned short* Wv2T  = p; p += 524288;    // [1024][512]
    unsigned short* qkv   = p; p += 12582912;  // [4096][3072]  (q | k-in | v-in)
    unsigned short* tmpb  = p; p += 4194304;   // [4096][1024]  (k1 | v1), reused as attn
    unsigned short* kvo   = p; p += 8388608;   // [4096][2048]  (k | v)
    unsigned short* vtb   = p; p += 4194304;   // [32*64][2048]
    unsigned short* attnb = tmpb;              // alias: tmp dead after k2v2

    dim3 blk(256);
    const float qscale = 0.125f * 1.44269504f;  // Dh^-0.5 * log2(e)

    cvt_x_kernel<<<4096, blk, 0, stream>>>(x, xb);
    transpose_w2_kernel<<<dim3(16, 16, 2), blk, 0, stream>>>(Wq, Wo, WqkvT, WoT, 1024, 1024, qscale, 1.0f);
    transpose_w2_kernel<<<dim3(32, 16, 1), blk, 0, stream>>>(Wkv, Wkv, WqkvT + 1048576, WqkvT + 1048576, 1024, 2048, 1.0f, 1.0f);
    transpose_w2_kernel<<<dim3(8, 16, 2),  blk, 0, stream>>>(Wk1, Wv1, Wk1T, Wv1T, 1024, 512, 1.0f, 1.0f);
    transpose_w2_kernel<<<dim3(16, 8, 2),  blk, 0, stream>>>(Wk2, Wv2, Wk2T, Wv2T, 512, 1024, 1.0f, 1.0f);

    // qkv = x @ [Wq*s | Wkv]   -> qkv [4096][3072]
    gemm_bf16_kernel<<<dim3(24, 32, 1), blk, 0, stream>>>(
        xb, xb, WqkvT, WqkvT, qkv, qkv, 1024, 1024, 3072, 1024, nullptr, 0, 0);
    // k1 = relu(kv_k @ Wk1), v1 = relu(kv_v @ Wv1)  -> tmpb [4096][512|512]
    gemm_bf16_kernel<<<dim3(4, 32, 2), blk, 0, stream>>>(
        qkv + 1024, qkv + 2048, Wk1T, Wv1T, tmpb, tmpb + 512,
        3072, 1024, 1024, 1024, nullptr, 1, 0);
    // k = k1 @ Wk2, v = v1 @ Wv2  -> kvo [4096][1024|1024]   (ldb = 512)
    gemm_bf16_kernel<<<dim3(8, 32, 2), blk, 0, stream>>>(
        tmpb, tmpb + 512, Wk2T, Wv2T, kvo, kvo + 1024,
        1024, 512, 2048, 512, nullptr, 0, 0);

    transpose_v_kernel<<<dim3(32, 32), blk, 0, stream>>>(kvo + 1024, 2048, vtb);
    flash_mfma_kernel<<<dim3(32, 32), blk, 0, stream>>>(qkv, 3072, kvo, 2048, vtb, attnb);
    // out = attn @ Wo + bo (fp32)
    gemm_bf16_kernel<<<dim3(8, 32, 1), blk, 0, stream>>>(
        attnb, attnb, WoT, WoT, out, out, 1024, 1024, 1024, 1024, bo, 0, 1);
}

// Round 7
// 359.735 us; speedup vs baseline: 1.4456x; 1.4456x over previous
//
#include <hip/hip_runtime.h>
#include <stdint.h>

// MLA bf16-MFMA pipeline R7. B=2, N=2048, D=1024, L=512, H=16, Dh=64.
// Flash v3: barrier-free, register double-buffered K/V prefetch (1-iter
// distance -> vmcnt(16) pipelining), 32 q-rows/wave (2 subs, halves traffic),
// S^T = K*Q^T for within-lane softmax, O^T = V^T*P^T so alpha/l are per-lane
// (no shuffles) and O stores vectorize. LDS = P roundtrip only (18 KB).
// GEMM pipeline unchanged from R5 (known good).

typedef __attribute__((ext_vector_type(8))) __bf16 bf16x8;
typedef __attribute__((ext_vector_type(4))) float f32x4;

__device__ inline unsigned short f2bfu(float f) {
    __bf16 b = (__bf16)f;
    return __builtin_bit_cast(unsigned short, b);
}

__device__ inline float exp2_fast(float f) {
    return __builtin_amdgcn_exp2f(f);   // raw v_exp_f32
}

__device__ inline void load_lds16(const void* g, void* l) {
    __builtin_amdgcn_global_load_lds(
        (const __attribute__((address_space(1))) uint32_t*)g,
        (__attribute__((address_space(3))) uint32_t*)l, 16, 0, 0);
}

__device__ inline f32x4 mfma_bf16(bf16x8 a, bf16x8 b, f32x4 c) {
    return __builtin_amdgcn_mfma_f32_16x16x32_bf16(a, b, c, 0, 0, 0);
}

// ---------------- prep kernels ----------------

__global__ __launch_bounds__(256) void cvt_x_kernel(
    const float* __restrict__ src, unsigned short* __restrict__ dst)
{
    int i = (blockIdx.x * 256 + threadIdx.x) * 4;
    float4 v = *(const float4*)&src[i];
    ushort4 o;
    o.x = f2bfu(v.x); o.y = f2bfu(v.y); o.z = f2bfu(v.z); o.w = f2bfu(v.w);
    *(ushort4*)&dst[i] = o;
}

// z-batched: src f32 [R][C] -> dst bf16 [C][R] * scale. grid (C/64, R/64, nz)
__global__ __launch_bounds__(256) void transpose_w2_kernel(
    const float* __restrict__ s0, const float* __restrict__ s1,
    unsigned short* __restrict__ d0, unsigned short* __restrict__ d1,
    int R, int C, float sc0, float sc1)
{
    const float* src = blockIdx.z ? s1 : s0;
    unsigned short* dst = blockIdx.z ? d1 : d0;
    float sc = blockIdx.z ? sc1 : sc0;
    __shared__ float tile[64][65];
    int c0 = blockIdx.x * 64, r0 = blockIdx.y * 64;
    int t = threadIdx.x;
    int col = t & 63, rr = t >> 6;
#pragma unroll
    for (int i = 0; i < 16; ++i)
        tile[rr + i * 4][col] = src[(size_t)(r0 + rr + i * 4) * C + c0 + col];
    __syncthreads();
#pragma unroll
    for (int i = 0; i < 16; ++i) {
        int r2 = rr + i * 4;
        dst[(size_t)(c0 + r2) * R + r0 + col] = f2bfu(tile[col][r2] * sc);
    }
}

// v[b][n][h*64+d] (ld ldv) bf16 -> vt[(b*16+h)*64+d][n]. grid (2048/64, 32)
__global__ __launch_bounds__(256) void transpose_v_kernel(
    const unsigned short* __restrict__ v, int ldv, unsigned short* __restrict__ vt)
{
    __shared__ unsigned short tile[64][65];
    int n0 = blockIdx.x * 64, bh = blockIdx.y;
    int b = bh >> 4, h = bh & 15;
    int t = threadIdx.x;
    int r = t >> 3, c = t & 7;
#pragma unroll
    for (int p = 0; p < 2; ++p) {
        int row = r + p * 32;
        const unsigned short* src = v + (size_t)(b * 2048 + n0 + row) * ldv + h * 64 + c * 8;
        ushort4 a = *(const ushort4*)src;
        ushort4 b4 = *(const ushort4*)(src + 4);
        tile[row][c * 8 + 0] = a.x;  tile[row][c * 8 + 1] = a.y;
        tile[row][c * 8 + 2] = a.z;  tile[row][c * 8 + 3] = a.w;
        tile[row][c * 8 + 4] = b4.x; tile[row][c * 8 + 5] = b4.y;
        tile[row][c * 8 + 6] = b4.z; tile[row][c * 8 + 7] = b4.w;
    }
    __syncthreads();
#pragma unroll
    for (int p = 0; p < 2; ++p) {
        int d = r + p * 32;
        ushort4 o0, o1;
        o0.x = tile[c * 8 + 0][d]; o0.y = tile[c * 8 + 1][d];
        o0.z = tile[c * 8 + 2][d]; o0.w = tile[c * 8 + 3][d];
        o1.x = tile[c * 8 + 4][d]; o1.y = tile[c * 8 + 5][d];
        o1.z = tile[c * 8 + 6][d]; o1.w = tile[c * 8 + 7][d];
        unsigned short* dp = vt + (size_t)(bh * 64 + d) * 2048 + n0 + c * 8;
        *(ushort4*)dp = o0;
        *(ushort4*)(dp + 4) = o1;
    }
}

// ---------------- bf16 MFMA GEMM (m97 structure, z-batched) ----------------
// C[M][N] = A[M][K] @ Bt[N][K]^T (+bias)(relu). 128x128 tile, BK=32.
// grid (N/128, M/128, nz), block 256.
__global__ __launch_bounds__(256) void gemm_bf16_kernel(
    const unsigned short* __restrict__ A0, const unsigned short* __restrict__ A1,
    const unsigned short* __restrict__ B0, const unsigned short* __restrict__ B1,
    void* __restrict__ C0, void* __restrict__ C1,
    int lda, int ldb, int ldc, int K,
    const float* __restrict__ bias, int relu, int out_f32)
{
    const unsigned short* A = blockIdx.z ? A1 : A0;
    const unsigned short* Bt = blockIdx.z ? B1 : B0;
    void* C = blockIdx.z ? C1 : C0;

    __shared__ unsigned short Als[128 * 32];
    __shared__ unsigned short Bls[128 * 32];
    int t = threadIdx.x;
    int lane = t & 63, w = t >> 6;
    int n0 = blockIdx.x * 128, m0 = blockIdx.y * 128;
    int wm = (w & 1) * 64, wn = (w >> 1) * 64;
    int lrow = lane & 15, quad = lane >> 4;

    f32x4 acc[4][4];
    f32x4 z = {0.f, 0.f, 0.f, 0.f};
#pragma unroll
    for (int i = 0; i < 4; ++i)
#pragma unroll
        for (int j = 0; j < 4; ++j) acc[i][j] = z;

    int c0 = t, c1 = t + 256;
    const unsigned short* ag0 = A + (size_t)(m0 + (c0 >> 2)) * lda + (c0 & 3) * 8;
    const unsigned short* ag1 = A + (size_t)(m0 + (c1 >> 2)) * lda + (c1 & 3) * 8;
    const unsigned short* bg0 = Bt + (size_t)(n0 + (c0 >> 2)) * ldb + (c0 & 3) * 8;
    const unsigned short* bg1 = Bt + (size_t)(n0 + (c1 >> 2)) * ldb + (c1 & 3) * 8;

    for (int k0 = 0; k0 < K; k0 += 32) {
        __syncthreads();
        load_lds16(ag0 + k0, &Als[c0 * 8]);
        load_lds16(ag1 + k0, &Als[c1 * 8]);
        load_lds16(bg0 + k0, &Bls[c0 * 8]);
        load_lds16(bg1 + k0, &Bls[c1 * 8]);
        __syncthreads();

        bf16x8 af[4], bfr[4];
#pragma unroll
        for (int mi = 0; mi < 4; ++mi)
            af[mi] = *(const bf16x8*)&Als[(wm + mi * 16 + lrow) * 32 + quad * 8];
#pragma unroll
        for (int ni = 0; ni < 4; ++ni)
            bfr[ni] = *(const bf16x8*)&Bls[(wn + ni * 16 + lrow) * 32 + quad * 8];
#pragma unroll
        for (int mi = 0; mi < 4; ++mi)
#pragma unroll
            for (int ni = 0; ni < 4; ++ni)
                acc[mi][ni] = mfma_bf16(af[mi], bfr[ni], acc[mi][ni]);
    }

#pragma unroll
    for (int mi = 0; mi < 4; ++mi)
#pragma unroll
        for (int ni = 0; ni < 4; ++ni)
#pragma unroll
            for (int r = 0; r < 4; ++r) {
                int row = m0 + wm + mi * 16 + quad * 4 + r;
                int col = n0 + wn + ni * 16 + lrow;
                float v = acc[mi][ni][r];
                if (bias) v += bias[col];
                if (relu) v = fmaxf(v, 0.0f);
                if (out_f32) ((float*)C)[(size_t)row * ldc + col] = v;
                else ((unsigned short*)C)[(size_t)row * ldc + col] = f2bfu(v);
            }
}

// ---------------- MFMA flash attention v3 ----------------
// Q: [4096][3072] (q cols h*64, pre-scaled by 0.125*log2e); K: [4096][2048]
// (k cols h*64); Vt: [32*64][2048]. grid (2048/128, 32), block 256 (4 waves).
// Wave w owns q-rows q0+w*32..+31 as two 16-row subs. Barrier-free:
// K/V fragments double-buffered in VGPRs with 1-iteration prefetch.
__global__ __launch_bounds__(256, 2) void flash_mfma_kernel(
    const unsigned short* __restrict__ Q,
    const unsigned short* __restrict__ K,
    const unsigned short* __restrict__ Vt,
    unsigned short* __restrict__ O)
{
    __shared__ unsigned short Pls[8][16 * 72];  // [wave*2+sub][q16][kv stride 72]

    const int q0 = blockIdx.x * 128, bh = blockIdx.y;
    const int b = bh >> 4, h = bh & 15;
    const int t = threadIdx.x, lane = t & 63, w = t >> 6;
    const int lrow = lane & 15, quad = lane >> 4;

    // Q frags (B-operand: B[k=d][n=q], lane holds Q[q=lrow][d=quad*8+j])
    bf16x8 qf[2][2];
#pragma unroll
    for (int s = 0; s < 2; ++s) {
        const unsigned short* qr =
            Q + (size_t)(b * 2048 + q0 + w * 32 + s * 16 + lrow) * 3072 + h * 64;
        qf[s][0] = *(const bf16x8*)&qr[quad * 8];
        qf[s][1] = *(const bf16x8*)&qr[32 + quad * 8];
    }

    const f32x4 z = {0.f, 0.f, 0.f, 0.f};
    f32x4 acco[2][4];   // [sub][nt]: O[q=lrow][d=nt*16+quad*4+r]
#pragma unroll
    for (int s = 0; s < 2; ++s)
#pragma unroll
        for (int nt = 0; nt < 4; ++nt) acco[s][nt] = z;
    float m_run[2] = {-1e30f, -1e30f};
    float l_run[2] = {0.f, 0.f};

    const unsigned short* kb = K + (size_t)(b * 2048 + lrow) * 2048 + h * 64 + quad * 8;
    const unsigned short* vb = Vt + (size_t)(bh * 64 + lrow) * 2048 + quad * 8;

    bf16x8 kf[2][4][2], vf[2][4][2];   // [buf][nt][half]

    auto LOAD = [&](int kt, int bu) {
#pragma unroll
        for (int nt = 0; nt < 4; ++nt) {
            const unsigned short* kr = kb + (size_t)(kt + nt * 16) * 2048;
            kf[bu][nt][0] = *(const bf16x8*)kr;
            kf[bu][nt][1] = *(const bf16x8*)(kr + 32);
            const unsigned short* vr = vb + (size_t)(nt * 16) * 2048 + kt;
            vf[bu][nt][0] = *(const bf16x8*)vr;
            vf[bu][nt][1] = *(const bf16x8*)(vr + 32);
        }
    };

    auto COMPUTE = [&](int bu) {
#pragma unroll
        for (int s = 0; s < 2; ++s) {
            // S^T = K * Q^T: lane holds S^T[kv=nt*16+quad*4+r][q=lrow]
            f32x4 sc[4];
#pragma unroll
            for (int nt = 0; nt < 4; ++nt) {
                sc[nt] = mfma_bf16(kf[bu][nt][0], qf[s][0], z);
                sc[nt] = mfma_bf16(kf[bu][nt][1], qf[s][1], sc[nt]);
            }
            // online softmax (log2 domain), kv split lane(16)/quads(x4)
            float mx = -1e30f;
#pragma unroll
            for (int nt = 0; nt < 4; ++nt)
#pragma unroll
                for (int r = 0; r < 4; ++r) mx = fmaxf(mx, sc[nt][r]);
            mx = fmaxf(mx, __shfl_xor(mx, 16, 64));
            mx = fmaxf(mx, __shfl_xor(mx, 32, 64));
            float mnew = fmaxf(m_run[s], mx);
            float al = exp2_fast(m_run[s] - mnew);
            m_run[s] = mnew;
            float rs = 0.f;
#pragma unroll
            for (int nt = 0; nt < 4; ++nt)
#pragma unroll
                for (int r = 0; r < 4; ++r) {
                    float pv = exp2_fast(sc[nt][r] - mnew);
                    sc[nt][r] = pv;
                    rs += pv;
                }
            rs += __shfl_xor(rs, 16, 64);
            rs += __shfl_xor(rs, 32, 64);
            l_run[s] = l_run[s] * al + rs;
            // alpha is per-lane (q=lrow) — matches acco's n-index, no shuffle
#pragma unroll
            for (int nt = 0; nt < 4; ++nt)
#pragma unroll
                for (int r = 0; r < 4; ++r) acco[s][nt][r] *= al;

            // P roundtrip (wave-local): write [q=lrow][kv], read B-operand frag
            unsigned short* P = Pls[w * 2 + s];
#pragma unroll
            for (int nt = 0; nt < 4; ++nt) {
                ushort4 pk;
                pk.x = f2bfu(sc[nt][0]); pk.y = f2bfu(sc[nt][1]);
                pk.z = f2bfu(sc[nt][2]); pk.w = f2bfu(sc[nt][3]);
                *(ushort4*)&P[lrow * 72 + nt * 16 + quad * 4] = pk;
            }
            bf16x8 pf0 = *(const bf16x8*)&P[lrow * 72 + quad * 8];
            bf16x8 pf1 = *(const bf16x8*)&P[lrow * 72 + 32 + quad * 8];

            // O^T += V^T * P^T  (A = Vt rows, B = pf; C: n=q per-lane)
#pragma unroll
            for (int nt = 0; nt < 4; ++nt) {
                acco[s][nt] = mfma_bf16(vf[bu][nt][0], pf0, acco[s][nt]);
                acco[s][nt] = mfma_bf16(vf[bu][nt][1], pf1, acco[s][nt]);
            }
        }
    };

    LOAD(0, 0);
    for (int kt = 0; kt < 2048; kt += 128) {
        LOAD(kt + 64, 1);          // prefetch while computing buf0
        COMPUTE(0);
        int ktn = (kt + 128 < 2048) ? kt + 128 : 0;   // last prefetch wraps (harmless)
        LOAD(ktn, 0);
        COMPUTE(1);
    }

    // epilogue: per-lane 1/l (q=lrow), vectorized b64 stores
#pragma unroll
    for (int s = 0; s < 2; ++s) {
        float rl = 1.0f / l_run[s];
        unsigned short* orow =
            O + (size_t)(b * 2048 + q0 + w * 32 + s * 16 + lrow) * 1024 + h * 64;
#pragma unroll
        for (int nt = 0; nt < 4; ++nt) {
            ushort4 o4;
            o4.x = f2bfu(acco[s][nt][0] * rl);
            o4.y = f2bfu(acco[s][nt][1] * rl);
            o4.z = f2bfu(acco[s][nt][2] * rl);
            o4.w = f2bfu(acco[s][nt][3] * rl);
            *(ushort4*)&orow[nt * 16 + quad * 4] = o4;
        }
    }
}

// ---------------- launch ----------------

extern "C" void kernel_launch(void* const* d_in, const int* in_sizes, int n_in,
                              void* d_out, int out_size, void* d_ws, size_t ws_size,
                              hipStream_t stream) {
    const float* x   = (const float*)d_in[0];
    const float* Wq  = (const float*)d_in[1];
    const float* Wkv = (const float*)d_in[2];
    const float* Wk1 = (const float*)d_in[3];
    const float* Wk2 = (const float*)d_in[4];
    const float* Wv1 = (const float*)d_in[5];
    const float* Wv2 = (const float*)d_in[6];
    const float* Wo  = (const float*)d_in[7];
    const float* bo  = (const float*)d_in[8];
    float* out = (float*)d_out;

    unsigned short* p = (unsigned short*)d_ws;
    unsigned short* xb    = p; p += 4194304;   // [4096][1024]
    unsigned short* WqkvT = p; p += 3145728;   // [3072][1024]  (Wq^T scaled | Wkv^T)
    unsigned short* WoT   = p; p += 1048576;   // [1024][1024]
    unsigned short* Wk1T  = p; p += 524288;    // [512][1024]
    unsigned short* Wv1T  = p; p += 524288;    // [512][1024]
    unsigned short* Wk2T  = p; p += 524288;    // [1024][512]
    unsigned short* Wv2T  = p; p += 524288;    // [1024][512]
    unsigned short* qkv   = p; p += 12582912;  // [4096][3072]  (q | k-in | v-in)
    unsigned short* tmpb  = p; p += 4194304;   // [4096][1024]  (k1 | v1), reused as attn
    unsigned short* kvo   = p; p += 8388608;   // [4096][2048]  (k | v)
    unsigned short* vtb   = p; p += 4194304;   // [32*64][2048]
    unsigned short* attnb = tmpb;              // alias: tmp dead after k2v2

    dim3 blk(256);
    const float qscale = 0.125f * 1.44269504f;  // Dh^-0.5 * log2(e)

    cvt_x_kernel<<<4096, blk, 0, stream>>>(x, xb);
    transpose_w2_kernel<<<dim3(16, 16, 2), blk, 0, stream>>>(Wq, Wo, WqkvT, WoT, 1024, 1024, qscale, 1.0f);
    transpose_w2_kernel<<<dim3(32, 16, 1), blk, 0, stream>>>(Wkv, Wkv, WqkvT + 1048576, WqkvT + 1048576, 1024, 2048, 1.0f, 1.0f);
    transpose_w2_kernel<<<dim3(8, 16, 2),  blk, 0, stream>>>(Wk1, Wv1, Wk1T, Wv1T, 1024, 512, 1.0f, 1.0f);
    transpose_w2_kernel<<<dim3(16, 8, 2),  blk, 0, stream>>>(Wk2, Wv2, Wk2T, Wv2T, 512, 1024, 1.0f, 1.0f);

    // qkv = x @ [Wq*s | Wkv]   -> qkv [4096][3072]
    gemm_bf16_kernel<<<dim3(24, 32, 1), blk, 0, stream>>>(
        xb, xb, WqkvT, WqkvT, qkv, qkv, 1024, 1024, 3072, 1024, nullptr, 0, 0);
    // k1 = relu(kv_k @ Wk1), v1 = relu(kv_v @ Wv1)  -> tmpb [4096][512|512]
    gemm_bf16_kernel<<<dim3(4, 32, 2), blk, 0, stream>>>(
        qkv + 1024, qkv + 2048, Wk1T, Wv1T, tmpb, tmpb + 512,
        3072, 1024, 1024, 1024, nullptr, 1, 0);
    // k = k1 @ Wk2, v = v1 @ Wv2  -> kvo [4096][1024|1024]   (ldb = 512)
    gemm_bf16_kernel<<<dim3(8, 32, 2), blk, 0, stream>>>(
        tmpb, tmpb + 512, Wk2T, Wv2T, kvo, kvo + 1024,
        1024, 512, 2048, 512, nullptr, 0, 0);

    transpose_v_kernel<<<dim3(32, 32), blk, 0, stream>>>(kvo + 1024, 2048, vtb);
    flash_mfma_kernel<<<dim3(16, 32), blk, 0, stream>>>(qkv, kvo, vtb, attnb);
    // out = attn @ Wo + bo (fp32)
    gemm_bf16_kernel<<<dim3(8, 32, 1), blk, 0, stream>>>(
        attnb, attnb, WoT, WoT, out, out, 1024, 1024, 1024, 1024, bo, 0, 1);
}